// Round 10
// baseline (181.986 us; speedup 1.0000x reference)
//
#include <hip/hip_runtime.h>

// Fused LSTM (B=4096, T=256, I=128, H=64) + projection (O=10).
// 512 WGs x 256 threads (4 waves), 2 WGs/CU: two independent recurrences per
// CU hide each other's recurrence-chain stalls (independent barriers).
// Each WG owns 8 batch rows; 16-row MFMA tile packs TWO timesteps
// (tile row tr = 4*a+u: u in {0,1} = step-even rows, +2 = step-odd rows,
// same batch 2*a+u in the same lane for both steps -> c-state in-lane).
// One 16-MFMA x-GEMM per 2 steps; per-step h-MFMAs use half-zeroed h tiles
// (hA: even rows valid, hB: odd rows valid). log2e-prescaled weights;
// shared-rcp algebra (7 trans/(b,j)).
// R10 vs R9: (a) zero ALL LDS before staging (uninit-LDS garbage was the
// remaining NaN candidate -- any mis-scheduled read now yields 0);
// (b) clamped transcendentals: fexp2 arg clamped to +-40, c clamped to
// +-30 via IEEE fminf/fmaxf (also NaN-killing) -> NaN impossible by
// construction; clamps are inert on real data (|args| <= ~25).

typedef __attribute__((ext_vector_type(8))) short bf16x8;
typedef __attribute__((ext_vector_type(4))) float f32x4;
typedef __attribute__((ext_vector_type(2))) unsigned u32x2;

#define T_STEPS 256
#define L2E 1.44269504f

#define XF_OFF 0          // 4 x 4096B bf16 x-frag ring (one slot = 2 steps)
#define HA_OFF 16384      // 2048B h tile A (even-step rows valid, odd zero)
#define HB_OFF 18432      // 2048B h tile B (odd-step rows valid, even zero)
#define HF_OFF 20480      // 2048B fp32 final h (8 rows x 64)
#define LDS_SZ 22528

__device__ __forceinline__ short f2bf(float f) {           // prologue only
    unsigned u = __float_as_uint(f);
    u += 0x7FFFu + ((u >> 16) & 1u);
    return (short)(u >> 16);
}
__device__ __forceinline__ unsigned cvt_pk(float lo, float hi) {
    unsigned r;
    asm("v_cvt_pk_bf16_f32 %0, %1, %2" : "=v"(r) : "v"(lo), "v"(hi));
    return r;
}
__device__ __forceinline__ float frcp(float x) { float r; asm("v_rcp_f32 %0, %1" : "=v"(r) : "v"(x)); return r; }
__device__ __forceinline__ float fexp2_raw(float x) { float r; asm("v_exp_f32 %0, %1" : "=v"(r) : "v"(x)); return r; }
// Clamped exp2: arg limited to +-40 (inert on real data, |arg|<=~25);
// fminf/fmaxf are IEEE minNum/maxNum -> they also neutralize NaN inputs.
__device__ __forceinline__ float fexp2c(float x) {
    return fexp2_raw(fminf(fmaxf(x, -40.0f), 40.0f));
}

#define MF(A, Bf, C) (C) = __builtin_amdgcn_mfma_f32_16x16x32_bf16((A), (Bf), (C), 0, 0, 0)
#define SYNC __syncthreads();

__global__ __launch_bounds__(256, 2) void lstm_kernel(
    const float* __restrict__ x,
    const float* __restrict__ W_ih,
    const float* __restrict__ W_hh,
    const float* __restrict__ b_ih,
    const float* __restrict__ b_hh,
    const float* __restrict__ W_out,
    const float* __restrict__ b_out,
    float* __restrict__ out)
{
    __shared__ __align__(16) char smem[LDS_SZ];

    const int tid  = threadIdx.x;
    const int lane = tid & 63;
    const int q    = tid >> 6;
    const int l15  = lane & 15;
    const int l4   = lane >> 4;
    const int b0   = blockIdx.x * 8;

    // ---------------- zero ALL LDS (kill uninit garbage) ----------------
    {
        const f32x4 z = (f32x4){0.f, 0.f, 0.f, 0.f};
        for (int i = tid; i < LDS_SZ / 16; i += 256)
            ((f32x4*)smem)[i] = z;
    }
    SYNC;

    // ---------------- weight fragments (exp2-prescaled) ----------------
    bf16x8 Bih[4][4];
    bf16x8 Bhh[4][2];
    f32x4  biasC[4];
#pragma unroll
    for (int nt = 0; nt < 4; ++nt) {
        const float scl = (nt == 2) ? (2.0f * L2E) : (-L2E);
        const int row = nt * 64 + q * 16 + l15;
#pragma unroll
        for (int ks = 0; ks < 4; ++ks) {
            const float* p = W_ih + row * 128 + ks * 32 + l4 * 8;
            f32x4 a = *(const f32x4*)p;
            f32x4 b = *(const f32x4*)(p + 4);
            bf16x8 wv;
#pragma unroll
            for (int j = 0; j < 4; ++j) { wv[j] = f2bf(a[j] * scl); wv[4 + j] = f2bf(b[j] * scl); }
            Bih[nt][ks] = wv;
        }
#pragma unroll
        for (int ks = 0; ks < 2; ++ks) {
            const float* p = W_hh + row * 64 + ks * 32 + l4 * 8;
            f32x4 a = *(const f32x4*)p;
            f32x4 b = *(const f32x4*)(p + 4);
            bf16x8 wv;
#pragma unroll
            for (int j = 0; j < 4; ++j) { wv[j] = f2bf(a[j] * scl); wv[4 + j] = f2bf(b[j] * scl); }
            Bhh[nt][ks] = wv;
        }
        const float bb = (b_ih[row] + b_hh[row]) * scl;
        biasC[nt] = (f32x4){bb, bb, bb, bb};
    }

    // ---------------- address maps ----------------
    int xf_rd[4];
#pragma unroll
    for (int ks = 0; ks < 4; ++ks)
        xf_rd[ks] = (((ks * 64 + lane) * 16) ^ ((ks & 3) << 6));

    const int jcol = q * 16 + l15;
    int hbA_wr[2], hbB_wr[2];
#pragma unroll
    for (int u = 0; u < 2; ++u) {
        const int trA = l4 * 4 + u;        // even-step row, batch 2*l4+u
        const int trB = trA + 2;           // odd-step row, same batch
        hbA_wr[u] = ((trA * 128 + jcol * 2) ^ ((trA & 7) << 4) ^ ((trA >> 3) << 5));
        hbB_wr[u] = ((trB * 128 + jcol * 2) ^ ((trB & 7) << 4) ^ ((trB >> 3) << 5));
    }
    int hb_rd[2];
#pragma unroll
    for (int ks = 0; ks < 2; ++ks)
        hb_rd[ks] = ((l15 * 128 + ks * 64 + l4 * 16) ^ ((l15 & 7) << 4) ^ ((l15 >> 3) << 5));

    // x staging: thread (v = tid>>5 in [0,8), scc = tid&31) covers tile rows
    // tr0 = 4*(v>>1)+(v&1) (even-step) and tr0+2 (odd-step) of batch row
    // bs = 2*(v>>1)+(v&1) = v; 32 threads cover one 512B x row.
    const int v   = tid >> 5;
    const int scc = tid & 31;
    const int sks = scc >> 3;
    const int sl4 = (scc & 7) >> 1;
    const int sh  = scc & 1;
    const int tr0 = 4 * (v >> 1) + (v & 1);
    const int bs  = 2 * (v >> 1) + (v & 1);
    const int xf_wr0 = (((sks * 64 + sl4 * 16 + tr0) * 16 + sh * 8) ^ ((sks & 3) << 6));
    const int xf_wr1 = (((sks * 64 + sl4 * 16 + tr0 + 2) * 16 + sh * 8) ^ ((sks & 3) << 6));
    const float* xsrc = x + (size_t)(b0 + bs) * (T_STEPS * 128) + scc * 4;

    // ---------------- prologue ----------------
    // stage slot 0 = x(0,1), slot 1 = x(2,3)
#pragma unroll
    for (int s = 0; s < 2; ++s) {
        f32x4 ve = *(const f32x4*)(xsrc + (size_t)(2 * s) * 128);
        f32x4 vo = *(const f32x4*)(xsrc + (size_t)(2 * s + 1) * 128);
        u32x2 we; we.x = cvt_pk(ve[0], ve[1]); we.y = cvt_pk(ve[2], ve[3]);
        u32x2 wo; wo.x = cvt_pk(vo[0], vo[1]); wo.y = cvt_pk(vo[2], vo[3]);
        *(u32x2*)(smem + XF_OFF + s * 4096 + xf_wr0) = we;
        *(u32x2*)(smem + XF_OFF + s * 4096 + xf_wr1) = wo;
    }
    f32x4 P0 = *(const f32x4*)(xsrc + 4 * 128);    // x(4) -> slot 2 (win 0)
    f32x4 P1 = *(const f32x4*)(xsrc + 5 * 128);    // x(5)

    SYNC;

    float c[2]  = {0.f, 0.f};
    float hl[2] = {0.f, 0.f};

    f32x4 accA[4], accB[4];

#define XGEMM(ACC, XPTR)                                                       \
    {                                                                          \
        bf16x8 Ax0 = *(const bf16x8*)((XPTR) + xf_rd[0]);                      \
        bf16x8 Ax1 = *(const bf16x8*)((XPTR) + xf_rd[1]);                      \
        bf16x8 Ax2 = *(const bf16x8*)((XPTR) + xf_rd[2]);                      \
        bf16x8 Ax3 = *(const bf16x8*)((XPTR) + xf_rd[3]);                      \
        ACC[0] = biasC[0]; ACC[1] = biasC[1];                                  \
        ACC[2] = biasC[2]; ACC[3] = biasC[3];                                  \
        MF(Ax0, Bih[0][0], ACC[0]); MF(Ax0, Bih[1][0], ACC[1]);                \
        MF(Ax0, Bih[2][0], ACC[2]); MF(Ax0, Bih[3][0], ACC[3]);                \
        MF(Ax1, Bih[0][1], ACC[0]); MF(Ax1, Bih[1][1], ACC[1]);                \
        MF(Ax1, Bih[2][1], ACC[2]); MF(Ax1, Bih[3][1], ACC[3]);                \
        MF(Ax2, Bih[0][2], ACC[0]); MF(Ax2, Bih[1][2], ACC[1]);                \
        MF(Ax2, Bih[2][2], ACC[2]); MF(Ax2, Bih[3][2], ACC[3]);                \
        MF(Ax3, Bih[0][3], ACC[0]); MF(Ax3, Bih[1][3], ACC[1]);                \
        MF(Ax3, Bih[2][3], ACC[2]); MF(Ax3, Bih[3][3], ACC[3]);                \
    }

    XGEMM(accA, smem + XF_OFF);            // accA = bias + gx(0,1) [slot 0]

#define ALGEBRA(EI, EF, EG, EO, U)                                             \
    {                                                                          \
      float u_  = 1.0f + (EI);                                                 \
      float v_  = (EG) + 1.0f;                                                 \
      float w_  = 1.0f + (EF);                                                 \
      float uv_ = u_ * v_;                                                     \
      float num = __builtin_fmaf(c[U], uv_, ((EG) - 1.0f) * w_);               \
      c[U] = fminf(fmaxf(num * frcp(uv_ * w_), -30.0f), 30.0f);                \
      float E2_ = fexp2c(c[U] * (2.0f * L2E));                                 \
      hl[U] = (E2_ - 1.0f) * frcp((E2_ + 1.0f) * (1.0f + (EO)));               \
    }

    // Window W = steps (2W, 2W+1).
#define WINDOW(W, ACUR, ANXT)                                                  \
  {                                                                            \
    const char* xrd = smem + XF_OFF + ((((W) + 1) & 3) * 4096);                \
    char*       xwr = smem + XF_OFF + ((((W) + 2) & 3) * 4096);                \
    char* hA = smem + HA_OFF;                                                  \
    char* hB = smem + HB_OFF;                                                  \
    bf16x8 Ah0 = *(const bf16x8*)(hA + hb_rd[0]);                              \
    bf16x8 Ah1 = *(const bf16x8*)(hA + hb_rd[1]);                              \
    MF(Ah0, Bhh[0][0], ACUR[0]); MF(Ah0, Bhh[1][0], ACUR[1]);                  \
    MF(Ah0, Bhh[2][0], ACUR[2]); MF(Ah0, Bhh[3][0], ACUR[3]);                  \
    MF(Ah1, Bhh[0][1], ACUR[0]); MF(Ah1, Bhh[1][1], ACUR[1]);                  \
    MF(Ah1, Bhh[2][1], ACUR[2]); MF(Ah1, Bhh[3][1], ACUR[3]);                  \
    float Ei0 = fexp2c(ACUR[0][0]), Ei1 = fexp2c(ACUR[0][1]);                  \
    float Ef0 = fexp2c(ACUR[1][0]), Ef1 = fexp2c(ACUR[1][1]);                  \
    float Eg0 = fexp2c(ACUR[2][0]), Eg1 = fexp2c(ACUR[2][1]);                  \
    float Eo0 = fexp2c(ACUR[3][0]), Eo1 = fexp2c(ACUR[3][1]);                  \
    XGEMM(ANXT, xrd);                      /* gx(2W+2, 2W+3) */                \
    ALGEBRA(Ei0, Ef0, Eg0, Eo0, 0)                                             \
    ALGEBRA(Ei1, Ef1, Eg1, Eo1, 1)                                             \
    {                                                                          \
      unsigned wp = cvt_pk(hl[0], hl[1]);                                      \
      *(short*)(hB + hbB_wr[0]) = (short)wp;                                   \
      *(short*)(hB + hbB_wr[1]) = (short)(wp >> 16);                           \
    }                                                                          \
    SYNC;                                                                      \
    bf16x8 Bh0 = *(const bf16x8*)(hB + hb_rd[0]);                              \
    bf16x8 Bh1 = *(const bf16x8*)(hB + hb_rd[1]);                              \
    MF(Bh0, Bhh[0][0], ACUR[0]); MF(Bh0, Bhh[1][0], ACUR[1]);                  \
    MF(Bh0, Bhh[2][0], ACUR[2]); MF(Bh0, Bhh[3][0], ACUR[3]);                  \
    MF(Bh1, Bhh[0][1], ACUR[0]); MF(Bh1, Bhh[1][1], ACUR[1]);                  \
    MF(Bh1, Bhh[2][1], ACUR[2]); MF(Bh1, Bhh[3][1], ACUR[3]);                  \
    float Fi0 = fexp2c(ACUR[0][2]), Fi1 = fexp2c(ACUR[0][3]);                  \
    float Ff0 = fexp2c(ACUR[1][2]), Ff1 = fexp2c(ACUR[1][3]);                  \
    float Fg0 = fexp2c(ACUR[2][2]), Fg1 = fexp2c(ACUR[2][3]);                  \
    float Fo0 = fexp2c(ACUR[3][2]), Fo1 = fexp2c(ACUR[3][3]);                  \
    {                                                                          \
      u32x2 wv0; wv0.x = cvt_pk(P0[0], P0[1]); wv0.y = cvt_pk(P0[2], P0[3]);   \
      u32x2 wv1; wv1.x = cvt_pk(P1[0], P1[1]); wv1.y = cvt_pk(P1[2], P1[3]);   \
      *(u32x2*)(xwr + xf_wr0) = wv0;                                           \
      *(u32x2*)(xwr + xf_wr1) = wv1;                                           \
      const int tc = (2 * ((W) + 3)) & 255;                                    \
      P0 = *(const f32x4*)(xsrc + (size_t)tc * 128);                           \
      P1 = *(const f32x4*)(xsrc + (size_t)(tc + 1) * 128);                     \
    }                                                                          \
    ALGEBRA(Fi0, Ff0, Fg0, Fo0, 0)                                             \
    ALGEBRA(Fi1, Ff1, Fg1, Fo1, 1)                                             \
    {                                                                          \
      unsigned wp = cvt_pk(hl[0], hl[1]);                                      \
      *(short*)(hA + hbA_wr[0]) = (short)wp;                                   \
      *(short*)(hA + hbA_wr[1]) = (short)(wp >> 16);                           \
    }                                                                          \
    SYNC;                                                                      \
  }

    for (int w = 0; w < 128; w += 2) {
        WINDOW(w,     accA, accB);
        WINDOW(w + 1, accB, accA);
    }
#undef WINDOW
#undef XGEMM
#undef ALGEBRA

    // ---------------- epilogue: out = h_last @ W_out.T + b_out -------------
#pragma unroll
    for (int u = 0; u < 2; ++u) {
        const int b = 2 * l4 + u;
        *(float*)(smem + HF_OFF + (b * 64 + jcol) * 4) = hl[u];
    }
    SYNC;

    if (tid < 80) {
        const int b = tid / 10;
        const int o = tid - b * 10;
        const f32x4* hf = (const f32x4*)(smem + HF_OFF + b * 256);
        const f32x4* wr = (const f32x4*)(W_out + o * 64);
        float s = b_out[o];
#pragma unroll
        for (int j4 = 0; j4 < 16; ++j4) {
            f32x4 h4 = hf[j4];
            f32x4 w4 = wr[j4];
            s += h4[0] * w4[0] + h4[1] * w4[1] + h4[2] * w4[2] + h4[3] * w4[3];
        }
        out[(b0 + b) * 10 + o] = s;
    }
}

extern "C" void kernel_launch(void* const* d_in, const int* in_sizes, int n_in,
                              void* d_out, int out_size, void* d_ws, size_t ws_size,
                              hipStream_t stream) {
    const float* x     = (const float*)d_in[0];
    const float* W_ih  = (const float*)d_in[1];
    const float* W_hh  = (const float*)d_in[2];
    const float* b_ih  = (const float*)d_in[3];
    const float* b_hh  = (const float*)d_in[4];
    const float* W_out = (const float*)d_in[5];
    const float* b_out = (const float*)d_in[6];
    (void)in_sizes; (void)n_in; (void)out_size; (void)d_ws; (void)ws_size;

    lstm_kernel<<<dim3(512), dim3(256), 0, stream>>>(
        x, W_ih, W_hh, b_ih, b_hh, W_out, b_out, (float*)d_out);
}